// Round 13
// baseline (1761.788 us; speedup 1.0000x reference)
//
#include <hip/hip_runtime.h>
#include <cmath>

#define BS_TOK 32768      // B*S
#define DMODEL 512
#define NHEAD 8
#define DHEAD 64
#define NLAYER 3
#define FFDIM 2048
#define NCLS 6
#define BATCH 32
#define SEQ 1024
#define QKVW 1536         // 3*D

typedef short short8 __attribute__((ext_vector_type(8)));
typedef float float4v __attribute__((ext_vector_type(4)));
typedef unsigned int uint4v __attribute__((ext_vector_type(4)));
#define MFMA_BF16 __builtin_amdgcn_mfma_f32_16x16x32_bf16
#define QSCALE 0.18033688011112042f   // 0.125 * log2(e)

__device__ __forceinline__ unsigned short f2bf(float x) {
    return (unsigned short)((__float_as_uint(x) + 0x8000u) >> 16);  // round-half-away
}

__device__ __forceinline__ unsigned int cvt_pk_bf16(float a, float b) {
    unsigned int r;
    asm("v_cvt_pk_bf16_f32 %0, %1, %2" : "=v"(r) : "v"(a), "v"(b));
    return r;
}

// swap high 32 lanes of a with low 32 lanes of b (lane-bit5 <-> reg-index swap)
#define PL32(a, b) asm("v_permlane32_swap_b32 %0, %1" : "+v"(a), "+v"(b))
// swap odd 16-rows of a with even 16-rows of b (lane-bit4 <-> reg-index swap)
#define PL16(a, b) asm("v_permlane16_swap_b32 %0, %1" : "+v"(a), "+v"(b))

// async global -> LDS, 16B per lane; lds base must be wave-uniform (HW adds lane*16)
__device__ __forceinline__ void gload16(const unsigned short* g, unsigned short* l) {
    __builtin_amdgcn_global_load_lds(
        (const __attribute__((address_space(1))) unsigned int*)g,
        (__attribute__((address_space(3))) unsigned int*)l, 16, 0, 0);
}

// ---------------- embedding + sinusoidal PE -> X fp32 + Xb bf16 ----------------
__global__ __launch_bounds__(128) void embed_pe_kernel(const int* __restrict__ tokens,
                                                       const float* __restrict__ emb,
                                                       float* __restrict__ X,
                                                       unsigned short* __restrict__ Xb) {
    int t = blockIdx.x;
    int pos = t & (SEQ - 1);
    int tok = tokens[t];
    int d0 = threadIdx.x * 4;
    float4 e = *(const float4*)(emb + (size_t)tok * DMODEL + d0);
    const float c = -9.210340371976184f / 512.0f;
    float div0 = expf((float)d0 * c);
    float div1 = expf((float)(d0 + 2) * c);
    float a0 = (float)pos * div0;
    float a1 = (float)pos * div1;
    e.x += sinf(a0); e.y += cosf(a0);
    e.z += sinf(a1); e.w += cosf(a1);
    *(float4*)(X + (size_t)t * DMODEL + d0) = e;
    *(ushort4*)(Xb + (size_t)t * DMODEL + d0) =
        make_ushort4(f2bf(e.x), f2bf(e.y), f2bf(e.z), f2bf(e.w));
}

// ---------------- generic transpose+convert (fc_w): f32 [R][C] -> bf16 [C][R] ----------------
__global__ __launch_bounds__(256) void transcvt_kernel(const float* __restrict__ in,
                                                       unsigned short* __restrict__ out,
                                                       int R, int C) {
    __shared__ float t[32][33];
    size_t base = (size_t)blockIdx.z * R * C;
    int c0 = blockIdx.x * 32, r0 = blockIdx.y * 32;
    int tx = threadIdx.x & 31, ty = threadIdx.x >> 5;
#pragma unroll
    for (int i = 0; i < 4; i++)
        t[ty + i * 8][tx] = in[base + (size_t)(r0 + ty + i * 8) * C + c0 + tx];
    __syncthreads();
#pragma unroll
    for (int i = 0; i < 4; i++)
        out[base + (size_t)(c0 + ty + i * 8) * R + r0 + tx] = f2bf(t[tx][ty + i * 8]);
}

// ---------------- qkv_w transpose+convert with head-permute + Q prescale ----------------
// out[l][n][k]: n<512 -> Q (head h=n>>6, scaled), n<1024 -> K, else V.
__global__ __launch_bounds__(256) void transcvt_qkv_kernel(const float* __restrict__ in,
                                                           unsigned short* __restrict__ out) {
    __shared__ float t[32][33];
    int l = blockIdx.z;
    int n0 = blockIdx.x * 32, r0 = blockIdx.y * 32;
    int seg = n0 >> 9, nn = n0 & 511, h = nn >> 6, d0 = nn & 63;
    int c0 = h * 192 + seg * 64 + d0;
    float s = (seg == 0) ? QSCALE : 1.f;
    const float* inp = in + (size_t)l * DMODEL * QKVW;
    unsigned short* op = out + (size_t)l * QKVW * DMODEL;
    int tx = threadIdx.x & 31, ty = threadIdx.x >> 5;
#pragma unroll
    for (int i = 0; i < 4; i++)
        t[ty + i * 8][tx] = inp[(size_t)(r0 + ty + i * 8) * QKVW + c0 + tx];
    __syncthreads();
#pragma unroll
    for (int i = 0; i < 4; i++)
        op[(size_t)(n0 + ty + i * 8) * DMODEL + r0 + tx] = f2bf(t[tx][ty + i * 8] * s);
}

// ---------------- permuted (+scaled) qkv bias ----------------
__global__ __launch_bounds__(256) void permbias_kernel(const float* __restrict__ qkv_b,
                                                       float* __restrict__ pb) {
    int i = blockIdx.x * 256 + threadIdx.x;   // < L*1536
    int l = i / QKVW, n = i - l * QKVW;
    int seg = n >> 9, nn = n & 511, h = nn >> 6, d = nn & 63;
    float s = (seg == 0) ? QSCALE : 1.f;
    pb[i] = qkv_b[l * QKVW + h * 192 + seg * 64 + d] * s;
}

// ---------------- QKV GEMM: [M,1536]perm = Xb[M,512] @ Wt^T + pb ----------------
// 128x256 tile, 512 threads / 8 waves, wave = 64x64 (acc[4][4] = 64 regs).
// launch_bounds(512,4) = 128-reg cap -> 2 blocks/CU = 4 waves/SIMD.
// gload_lds staging, XOR source pre-swizzle, double-buffered, ONE barrier/K-step.
__global__ __launch_bounds__(512, 4) void gemm_qkv_kernel(const unsigned short* __restrict__ A,
                                                          const unsigned short* __restrict__ Bt,
                                                          const float* __restrict__ pb,
                                                          unsigned short* __restrict__ QKc,
                                                          unsigned short* __restrict__ Vt,
                                                          int M) {
    __shared__ unsigned short As[2][128 * 32];
    __shared__ unsigned short Bs[2][256 * 32];
    int bm = blockIdx.y * 128, bn = blockIdx.x * 256;
    int tid = threadIdx.x;
    int w = tid >> 6, lane = tid & 63, l15 = lane & 15, quad = lane >> 4;
    int wm = (w & 1) * 64, wn = (w >> 1) * 64;

    float4v acc[4][4];
    float4v z = {0.f, 0.f, 0.f, 0.f};
#pragma unroll
    for (int i = 0; i < 4; i++)
#pragma unroll
        for (int j = 0; j < 4; j++) acc[i][j] = z;

    // staging geometry: chunk ch covers rows [ch*16, ch*16+16); lane l -> row
    // ch*16 + l/4, pre-swizzled source 8-short chunk ((l&3) ^ ((l>>3)&3)).
    int rsub = lane >> 2;
    int sc = ((lane & 3) ^ ((lane >> 3) & 3)) * 8;
    const unsigned short* Ag = A + (size_t)bm * DMODEL;
    const unsigned short* Bg = Bt + (size_t)bn * DMODEL;

    // prologue: stage kt=0 into buf 0 (wave w: A chunk w, B chunks w and w+8)
    gload16(Ag + (size_t)(w * 16 + rsub) * DMODEL + sc, &As[0][w * 512]);
    gload16(Bg + (size_t)(w * 16 + rsub) * DMODEL + sc, &Bs[0][w * 512]);
    gload16(Bg + (size_t)((w + 8) * 16 + rsub) * DMODEL + sc, &Bs[0][(w + 8) * 512]);
    __syncthreads();

    int sw = (l15 >> 1) & 3;
    for (int kt = 0; kt < 16; kt++) {
        const unsigned short* Ac = As[kt & 1];
        const unsigned short* Bc = Bs[kt & 1];
        if (kt + 1 < 16) {
            int kn = (kt + 1) * 32;
            unsigned short* An = (unsigned short*)As[(kt + 1) & 1];
            unsigned short* Bn = (unsigned short*)Bs[(kt + 1) & 1];
            gload16(Ag + (size_t)(w * 16 + rsub) * DMODEL + kn + sc, &An[w * 512]);
            gload16(Bg + (size_t)(w * 16 + rsub) * DMODEL + kn + sc, &Bn[w * 512]);
            gload16(Bg + (size_t)((w + 8) * 16 + rsub) * DMODEL + kn + sc,
                    &Bn[(w + 8) * 512]);
        }
        short8 af[4], bf[4];
#pragma unroll
        for (int i = 0; i < 4; i++)
            af[i] = *(short8*)&Ac[(wm + i * 16 + l15) * 32 + (quad ^ sw) * 8];
#pragma unroll
        for (int j = 0; j < 4; j++)
            bf[j] = *(short8*)&Bc[(wn + j * 16 + l15) * 32 + (quad ^ sw) * 8];
        __builtin_amdgcn_s_setprio(1);
#pragma unroll
        for (int i = 0; i < 4; i++)
#pragma unroll
            for (int j = 0; j < 4; j++)
                acc[i][j] = MFMA_BF16(af[i], bf[j], acc[i][j], 0, 0, 0);
        __builtin_amdgcn_s_setprio(0);
        __syncthreads();
    }

    float bj[4];
#pragma unroll
    for (int j = 0; j < 4; j++) bj[j] = pb[bn + wn + j * 16 + l15];

    if (bn < 1024) {          // Q | K -> row-major QKc[tok][1024]
#pragma unroll
        for (int i = 0; i < 4; i++)
#pragma unroll
            for (int r = 0; r < 4; r++) {
                size_t row = (size_t)(bm + wm + i * 16 + quad * 4 + r);
#pragma unroll
                for (int j = 0; j < 4; j++)
                    QKc[row * 1024 + bn + wn + j * 16 + l15] = f2bf(acc[i][j][r] + bj[j]);
            }
    } else {                  // V -> transposed Vt[bh][d][s]
        int bl = bm >> 10;
        int sbase = (bm & 1023) + wm;
#pragma unroll
        for (int j = 0; j < 4; j++) {
            int colp = bn - 1024 + wn + j * 16 + l15;
            int h = colp >> 6, d = colp & 63;
            unsigned short* vb = Vt + ((size_t)(bl * 8 + h) * 64 + d) * 1024 + sbase;
#pragma unroll
            for (int i = 0; i < 4; i++) {
                ushort4 v4 = make_ushort4(f2bf(acc[i][j][0] + bj[j]),
                                          f2bf(acc[i][j][1] + bj[j]),
                                          f2bf(acc[i][j][2] + bj[j]),
                                          f2bf(acc[i][j][3] + bj[j]));
                *(ushort4*)(vb + i * 16 + quad * 4) = v4;
            }
        }
    }
}

// ---------------- bf16 MFMA flash attention, max-free softmax ----------------
// QKc [tok][Q512|K512] (Q pre-scaled by 0.125*log2e), Vt [bh][64][1024]. O bf16
// [tok][512]. QBLK=512, 512 threads / 8 waves (each wave: 64 q-rows, identical
// per-wave inner loop to the proven round-6 version). launch_bounds(512,4) ->
// 2 blocks/CU = 4 waves/SIMD (2x occupancy; latency was the attn binding
// constraint). K/V HBM refetch halves (2 q-block passes instead of 4); grid =
// 512 blocks = exactly one generation. Reg prefetch, swapped QK^T, in-register
// softmax via cvt_pk + permlane swaps.
__global__ __launch_bounds__(512, 4) void attn_kernel(const unsigned short* __restrict__ QKc,
                                                      const unsigned short* __restrict__ Vt,
                                                      unsigned short* __restrict__ O) {
    __shared__ unsigned short Ks[64 * 72];    // K[kcol][d]
    __shared__ unsigned short Vts[64 * 72];   // V^T[d][k]
    int bh = blockIdx.y;
    int b = bh >> 3, h = bh & 7;
    int q0 = blockIdx.x * 512;
    int tid = threadIdx.x;
    int w = tid >> 6, lane = tid & 63, l15 = lane & 15, quad = lane >> 4;
    const unsigned short* Kg = QKc + (size_t)b * SEQ * 1024 + 512 + h * 64;
    const unsigned short* Vg = Vt + (size_t)bh * 64 * 1024;

    short8 qf[4][2];
#pragma unroll
    for (int i = 0; i < 4; i++) {
        const unsigned short* qb =
            QKc + (size_t)(b * SEQ + q0 + w * 64 + i * 16 + l15) * 1024 + h * 64;
        qf[i][0] = *(const short8*)(qb + quad * 8);
        qf[i][1] = *(const short8*)(qb + 32 + quad * 8);
    }

    float lsum[4] = {0.f, 0.f, 0.f, 0.f};
    float4v accO[4][4];
    float4v z = {0.f, 0.f, 0.f, 0.f};
#pragma unroll
    for (int i = 0; i < 4; i++)
#pragma unroll
        for (int dc = 0; dc < 4; dc++) accO[i][dc] = z;

    int sr = tid >> 3, so = (tid & 7) * 8;   // staging: 512 thr x 16B = one tile

    // prefetch tile 0 into regs
    short8 kp, vp;
    {
        kp = *(const short8*)(Kg + (size_t)sr * 1024 + so);
        vp = *(const short8*)(Vg + (size_t)sr * 1024 + so);
    }

    for (int jt = 0; jt < SEQ / 64; jt++) {
        __syncthreads();
        *(short8*)&Ks[sr * 72 + so] = kp;
        *(short8*)&Vts[sr * 72 + so] = vp;
        __syncthreads();

        // prefetch next tile (latency hides under this tile's compute)
        if (jt + 1 < SEQ / 64) {
            kp = *(const short8*)(Kg + (size_t)((jt + 1) * 64 + sr) * 1024 + so);
            vp = *(const short8*)(Vg + (size_t)sr * 1024 + (jt + 1) * 64 + so);
        }

        // S^T: lane (l15,quad) reg r holds S[q=i*16+l15][k=jc*16+quad*4+r].
        // One kf pair feeds all 4 i's.
        short8 pa[4][2];
#pragma unroll
        for (int f = 0; f < 2; f++) {
            float4v st[4][2];
#pragma unroll
            for (int jj = 0; jj < 2; jj++) {
                int jc = f * 2 + jj;
                short8 kf0 = *(short8*)&Ks[(jc * 16 + l15) * 72 + quad * 8];
                short8 kf1 = *(short8*)&Ks[(jc * 16 + l15) * 72 + 32 + quad * 8];
#pragma unroll
                for (int i = 0; i < 4; i++) {
                    float4v s0 = MFMA_BF16(kf0, qf[i][0], z, 0, 0, 0);
                    st[i][jj] = MFMA_BF16(kf1, qf[i][1], s0, 0, 0, 0);
                }
            }
#pragma unroll
            for (int i = 0; i < 4; i++) {
                unsigned int pk[4];
#pragma unroll
                for (int jj = 0; jj < 2; jj++) {
                    float p0 = exp2f(st[i][jj][0]);
                    float p1 = exp2f(st[i][jj][1]);
                    float p2 = exp2f(st[i][jj][2]);
                    float p3 = exp2f(st[i][jj][3]);
                    lsum[i] += (p0 + p1) + (p2 + p3);
                    pk[jj * 2 + 0] = cvt_pk_bf16(p0, p1);
                    pk[jj * 2 + 1] = cvt_pk_bf16(p2, p3);
                }
                // dst(l5,l4,r1,r0) <- src(l4,r1,l5,r0): 2x permlane32 + 2x permlane16
                PL32(pk[0], pk[2]);
                PL32(pk[1], pk[3]);
                PL16(pk[0], pk[2]);
                PL16(pk[1], pk[3]);
                uint4v t;
                t[0] = pk[0]; t[1] = pk[1]; t[2] = pk[2]; t[3] = pk[3];
                pa[i][f] = __builtin_bit_cast(short8, t);
            }
        }

        // PV: one vf pair feeds all 4 i's
        __builtin_amdgcn_s_setprio(1);
#pragma unroll
        for (int dc = 0; dc < 4; dc++) {
            short8 vf0 = *(short8*)&Vts[(dc * 16 + l15) * 72 + quad * 8];
            short8 vf1 = *(short8*)&Vts[(dc * 16 + l15) * 72 + 32 + quad * 8];
#pragma unroll
            for (int i = 0; i < 4; i++) {
                accO[i][dc] = MFMA_BF16(pa[i][0], vf0, accO[i][dc], 0, 0, 0);
                accO[i][dc] = MFMA_BF16(pa[i][1], vf1, accO[i][dc], 0, 0, 0);
            }
        }
        __builtin_amdgcn_s_setprio(0);
    }

    // epilogue: reduce row sums across the 4 quads, fetch per-row sum, normalize
#pragma unroll
    for (int i = 0; i < 4; i++) {
        float s = lsum[i];
        s += __shfl_xor(s, 16);
        s += __shfl_xor(s, 32);   // all lanes now hold total for q = i*16 + l15
#pragma unroll
        for (int r = 0; r < 4; r++) {
            float rinv = 1.f / __shfl(s, quad * 4 + r);
            size_t row = (size_t)(b * SEQ + q0 + w * 64 + i * 16 + quad * 4 + r);
#pragma unroll
            for (int dc = 0; dc < 4; dc++)
                O[row * DMODEL + h * DHEAD + dc * 16 + l15] = f2bf(accO[i][dc][r] * rinv);
        }
    }
}

// ---------------- fused out-proj + bias + residual + LayerNorm ----------------
// (round-10 best-measured version) M=64 per block, 256 threads, acc[4][8];
// halves per-dispatch B-panel re-staging vs M=32 and doubles MFMA per B LDS-read.
// Post-residual values stored IN PLACE into acc. gload_lds staging,
// double-buffered, one barrier per K-step.
__global__ __launch_bounds__(256, 2) void proj_ln_kernel(const unsigned short* __restrict__ A,
                                                         const unsigned short* __restrict__ Bt,
                                                         const float* __restrict__ bias,
                                                         const float* __restrict__ gamma,
                                                         const float* __restrict__ beta,
                                                         float* __restrict__ X,
                                                         unsigned short* __restrict__ Xb) {
    __shared__ unsigned short As2[2][64 * 32];
    __shared__ unsigned short Bs2[2][512 * 32];
    __shared__ float redS[4][64], redQ[4][64];
    int bm = blockIdx.x * 64;
    int tid = threadIdx.x;
    int w = tid >> 6, lane = tid & 63, l15 = lane & 15, quad = lane >> 4;
    int wn = w * 128;

    float4v acc[4][8];
    float4v z = {0.f, 0.f, 0.f, 0.f};
#pragma unroll
    for (int i = 0; i < 4; i++)
#pragma unroll
        for (int j = 0; j < 8; j++) acc[i][j] = z;

    int lrow4 = lane >> 2;
    int sc = ((lane & 3) ^ ((lane >> 3) & 3)) * 8;
    const unsigned short* Ag = A + (size_t)bm * DMODEL;

    // prologue: stage kt=0 into buf 0 (wave w: A chunk w, B chunks w*8..w*8+7)
    gload16(Ag + (size_t)(w * 16 + lrow4) * DMODEL + sc, &As2[0][w * 512]);
#pragma unroll
    for (int u = 0; u < 8; u++) {
        int ch = w * 8 + u;
        gload16(Bt + (size_t)(ch * 16 + lrow4) * DMODEL + sc, &Bs2[0][ch * 512]);
    }
    __syncthreads();

    int sw = (l15 >> 1) & 3;
    for (int kt = 0; kt < 16; kt++) {
        const unsigned short* Ac = As2[kt & 1];
        const unsigned short* Bc = Bs2[kt & 1];
        if (kt + 1 < 16) {
            int kn = (kt + 1) * 32;
            unsigned short* An = (unsigned short*)As2[(kt + 1) & 1];
            unsigned short* Bn = (unsigned short*)Bs2[(kt + 1) & 1];
            gload16(Ag + (size_t)(w * 16 + lrow4) * DMODEL + kn + sc, &An[w * 512]);
#pragma unroll
            for (int u = 0; u < 8; u++) {
                int ch = w * 8 + u;
                gload16(Bt + (size_t)(ch * 16 + lrow4) * DMODEL + kn + sc, &Bn[ch * 512]);
            }
        }
        short8 af[4];
#pragma unroll
        for (int i = 0; i < 4; i++)
            af[i] = *(short8*)&Ac[(i * 16 + l15) * 32 + (quad ^ sw) * 8];
        __builtin_amdgcn_s_setprio(1);
#pragma unroll
        for (int j = 0; j < 8; j++) {
            short8 bf = *(short8*)&Bc[(wn + j * 16 + l15) * 32 + (quad ^ sw) * 8];
#pragma unroll
            for (int i = 0; i < 4; i++)
                acc[i][j] = MFMA_BF16(af[i], bf, acc[i][j], 0, 0, 0);
        }
        __builtin_amdgcn_s_setprio(0);
        __syncthreads();
    }

    float bj[8], g[8], be[8];
#pragma unroll
    for (int j = 0; j < 8; j++) {
        int col = wn + j * 16 + l15;
        bj[j] = bias[col]; g[j] = gamma[col]; be[j] = beta[col];
    }

#pragma unroll
    for (int i = 0; i < 4; i++)
#pragma unroll
        for (int r = 0; r < 4; r++) {
            int lrow = i * 16 + quad * 4 + r;
            size_t row = (size_t)(bm + lrow);
            float ss = 0.f, qq = 0.f;
#pragma unroll
            for (int j = 0; j < 8; j++) {
                float v = acc[i][j][r] + bj[j] + X[row * DMODEL + wn + j * 16 + l15];
                acc[i][j][r] = v;          // in-place: acc becomes post-residual o
                ss += v; qq += v * v;
            }
#pragma unroll
            for (int mask = 1; mask < 16; mask <<= 1) {
                ss += __shfl_xor(ss, mask);
                qq += __shfl_xor(qq, mask);
            }
            if (l15 == 0) { redS[w][lrow] = ss; redQ[w][lrow] = qq; }
        }
    __syncthreads();
#pragma unroll
    for (int i = 0; i < 4; i++)
#pragma unroll
        for (int r = 0; r < 4; r++) {
            int lrow = i * 16 + quad * 4 + r;
            float S = redS[0][lrow] + redS[1][lrow] + redS[2][lrow] + redS[3][lrow];
            float Q = redQ[0][lrow] + redQ[1][lrow] + redQ[2][lrow] + redQ[3][lrow];
            float mean = S * (1.f / 512.f);
            float var = Q * (1.f / 512.f) - mean * mean;
            float rstd = rsqrtf(var + 1e-5f);
            size_t row = (size_t)(bm + lrow);
#pragma unroll
            for (int j = 0; j < 8; j++) {
                float n = (acc[i][j][r] - mean) * rstd * g[j] + be[j];
                X[row * DMODEL + wn + j * 16 + l15] = n;
                Xb[row * DMODEL + wn + j * 16 + l15] = f2bf(n);
            }
        }
}

// ---------------- pooled zero + two-stage mean pool ----------------
__global__ __launch_bounds__(256) void zero_kernel(float* __restrict__ p) {
    p[blockIdx.x * 256 + threadIdx.x] = 0.f;
}
__global__ __launch_bounds__(128) void pool_kernel(const float* __restrict__ X,
                                                   float* __restrict__ pooled) {
    int b = blockIdx.x, ch = blockIdx.y;
    int d0 = threadIdx.x * 4;
    float4 acc = make_float4(0.f, 0.f, 0.f, 0.f);
    const float* base = X + (size_t)(b * SEQ + ch * 64) * DMODEL + d0;
    for (int s2 = 0; s2 < 64; s2++) {
        float4 v = *(const float4*)(base + (size_t)s2 * DMODEL);
        acc.x += v.x; acc.y += v.y; acc.z += v.z; acc.w += v.w;
    }
    atomicAdd(pooled + b * DMODEL + d0 + 0, acc.x);
    atomicAdd(pooled + b * DMODEL + d0 + 1, acc.y);
    atomicAdd(pooled + b * DMODEL + d0 + 2, acc.z);
    atomicAdd(pooled + b * DMODEL + d0 + 3, acc.w);
}

// ---------------- MLP head ----------------
__global__ __launch_bounds__(256) void fc1_kernel(const float* __restrict__ pooled,
                                                  const float* __restrict__ fc1_w,
                                                  const float* __restrict__ fc1_b,
                                                  float* __restrict__ h) {
    __shared__ float p[DMODEL];
    int ffc = blockIdx.x, b = blockIdx.y;
    int tid = threadIdx.x;
    p[tid] = pooled[b * DMODEL + tid] * (1.f / 1024.f);
    p[tid + 256] = pooled[b * DMODEL + tid + 256] * (1.f / 1024.f);
    __syncthreads();
    int ff = ffc * 256 + tid;
    float acc = fc1_b[ff];
    for (int k = 0; k < DMODEL; k++) acc += p[k] * fc1_w[(size_t)k * FFDIM + ff];
    h[(size_t)b * FFDIM + ff] = fmaxf(acc, 0.f);
}

__global__ __launch_bounds__(256) void fc2_kernel(const float* __restrict__ h,
                                                  const float* __restrict__ fc2_w,
                                                  const float* __restrict__ fc2_b,
                                                  float* __restrict__ out) {
    __shared__ float red[NCLS][256];
    int b = blockIdx.x, tid = threadIdx.x;
    float a[NCLS];
#pragma unroll
    for (int c = 0; c < NCLS; c++) a[c] = 0.f;
    int k0 = tid * 8;
#pragma unroll
    for (int u = 0; u < 8; u++) {
        float hv = h[(size_t)b * FFDIM + k0 + u];
#pragma unroll
        for (int c = 0; c < NCLS; c++) a[c] += hv * fc2_w[(k0 + u) * NCLS + c];
    }
#pragma unroll
    for (int c = 0; c < NCLS; c++) red[c][tid] = a[c];
    __syncthreads();
    if (tid < NCLS) {
        float s = 0.f;
        for (int i = 0; i < 256; i++) s += red[tid][i];
        out[b * NCLS + tid] = s + fc2_b[tid];
    }
}

extern "C" void kernel_launch(void* const* d_in, const int* in_sizes, int n_in,
                              void* d_out, int out_size, void* d_ws, size_t ws_size,
                              hipStream_t stream) {
    const int* tokens = (const int*)d_in[0];
    const float* emb = (const float*)d_in[1];
    const float* qkv_w = (const float*)d_in[2];
    const float* qkv_b = (const float*)d_in[3];
    const float* fc_w = (const float*)d_in[4];
    const float* fc_b = (const float*)d_in[5];
    const float* gamma = (const float*)d_in[6];
    const float* beta = (const float*)d_in[7];
    const float* fc1_w = (const float*)d_in[8];
    const float* fc1_b = (const float*)d_in[9];
    const float* fc2_w = (const float*)d_in[10];
    const float* fc2_b = (const float*)d_in[11];
    float* out = (float*)d_out;

    char* p = (char*)d_ws;
    float* X = (float*)p;                         p += (size_t)BS_TOK * DMODEL * 4;  // 64 MB
    unsigned short* Xb = (unsigned short*)p;      p += (size_t)BS_TOK * DMODEL * 2;  // 32 MB
    float* pooled = (float*)p;                    p += (size_t)BATCH * DMODEL * 4;
    float* hbuf = (float*)p;                      p += (size_t)BATCH * FFDIM * 4;
    float* pb = (float*)p;                        p += (size_t)NLAYER * QKVW * 4;
    unsigned short* qkv_wbt = (unsigned short*)p; p += (size_t)NLAYER * QKVW * DMODEL * 2;
    unsigned short* fc_wt = (unsigned short*)p;   p += (size_t)NLAYER * DMODEL * DMODEL * 2;
    size_t fixed_bytes = (size_t)(p - (char*)d_ws);
    // per batch: QKc 2MB + Vt 1MB + Oc 1MB
    size_t per_batch = (size_t)SEQ * 1024 * 2 + (size_t)NHEAD * 64 * SEQ * 2
                     + (size_t)SEQ * DMODEL * 2;
    int chunkB = 1;
    for (int cb = 32; cb >= 1; cb >>= 1)
        if (fixed_bytes + (size_t)cb * per_batch <= ws_size) { chunkB = cb; break; }
    unsigned short* QKc = (unsigned short*)p;     p += (size_t)chunkB * SEQ * 1024 * 2;
    unsigned short* Vt = (unsigned short*)p;      p += (size_t)chunkB * NHEAD * 64 * SEQ * 2;
    unsigned short* Oc = (unsigned short*)p;
    int rows = chunkB * SEQ;
    int nchunks = BATCH / chunkB;

    embed_pe_kernel<<<BS_TOK, 128, 0, stream>>>(tokens, emb, X, Xb);
    permbias_kernel<<<NLAYER * QKVW / 256, 256, 0, stream>>>(qkv_b, pb);
    transcvt_qkv_kernel<<<dim3(QKVW / 32, DMODEL / 32, NLAYER), 256, 0, stream>>>(
        qkv_w, qkv_wbt);
    transcvt_kernel<<<dim3(DMODEL / 32, DMODEL / 32, NLAYER), 256, 0, stream>>>(
        fc_w, fc_wt, DMODEL, DMODEL);

    for (int l = 0; l < NLAYER; l++) {
        for (int c = 0; c < nchunks; c++) {
            unsigned short* Xbc = Xb + (size_t)c * rows * DMODEL;
            float* Xc = X + (size_t)c * rows * DMODEL;
            gemm_qkv_kernel<<<dim3(QKVW / 256, rows / 128), 512, 0, stream>>>(
                Xbc, qkv_wbt + (size_t)l * QKVW * DMODEL, pb + (size_t)l * QKVW,
                QKc, Vt, rows);
            attn_kernel<<<dim3(SEQ / 512, chunkB * NHEAD), 512, 0, stream>>>(QKc, Vt, Oc);
            proj_ln_kernel<<<rows / 64, 256, 0, stream>>>(
                Oc, fc_wt + (size_t)l * DMODEL * DMODEL, fc_b + (size_t)l * DMODEL,
                gamma, beta, Xc, Xbc);
        }
    }

    zero_kernel<<<BATCH * DMODEL / 256, 256, 0, stream>>>(pooled);
    pool_kernel<<<dim3(BATCH, 16), 128, 0, stream>>>(X, pooled);
    fc1_kernel<<<dim3(FFDIM / 256, BATCH), 256, 0, stream>>>(pooled, fc1_w, fc1_b, hbuf);
    fc2_kernel<<<BATCH, 256, 0, stream>>>(hbuf, fc2_w, fc2_b, out);
}

// Round 14
// 843.021 us; speedup vs baseline: 2.0899x; 2.0899x over previous
//
#include <hip/hip_runtime.h>
#include <cmath>

#define BS_TOK 32768      // B*S
#define DMODEL 512
#define NHEAD 8
#define DHEAD 64
#define NLAYER 3
#define FFDIM 2048
#define NCLS 6
#define BATCH 32
#define SEQ 1024
#define QKVW 1536         // 3*D

typedef short short8 __attribute__((ext_vector_type(8)));
typedef float float4v __attribute__((ext_vector_type(4)));
typedef unsigned int uint4v __attribute__((ext_vector_type(4)));
#define MFMA_BF16 __builtin_amdgcn_mfma_f32_16x16x32_bf16
#define QSCALE 0.18033688011112042f   // 0.125 * log2(e)

__device__ __forceinline__ unsigned short f2bf(float x) {
    return (unsigned short)((__float_as_uint(x) + 0x8000u) >> 16);  // round-half-away
}

__device__ __forceinline__ unsigned int cvt_pk_bf16(float a, float b) {
    unsigned int r;
    asm("v_cvt_pk_bf16_f32 %0, %1, %2" : "=v"(r) : "v"(a), "v"(b));
    return r;
}

// swap high 32 lanes of a with low 32 lanes of b (lane-bit5 <-> reg-index swap)
#define PL32(a, b) asm("v_permlane32_swap_b32 %0, %1" : "+v"(a), "+v"(b))
// swap odd 16-rows of a with even 16-rows of b (lane-bit4 <-> reg-index swap)
#define PL16(a, b) asm("v_permlane16_swap_b32 %0, %1" : "+v"(a), "+v"(b))

// async global -> LDS, 16B per lane; lds base must be wave-uniform (HW adds lane*16)
__device__ __forceinline__ void gload16(const unsigned short* g, unsigned short* l) {
    __builtin_amdgcn_global_load_lds(
        (const __attribute__((address_space(1))) unsigned int*)g,
        (__attribute__((address_space(3))) unsigned int*)l, 16, 0, 0);
}

// ---------------- embedding + sinusoidal PE -> X fp32 + Xb bf16 ----------------
__global__ __launch_bounds__(128) void embed_pe_kernel(const int* __restrict__ tokens,
                                                       const float* __restrict__ emb,
                                                       float* __restrict__ X,
                                                       unsigned short* __restrict__ Xb) {
    int t = blockIdx.x;
    int pos = t & (SEQ - 1);
    int tok = tokens[t];
    int d0 = threadIdx.x * 4;
    float4 e = *(const float4*)(emb + (size_t)tok * DMODEL + d0);
    const float c = -9.210340371976184f / 512.0f;
    float div0 = expf((float)d0 * c);
    float div1 = expf((float)(d0 + 2) * c);
    float a0 = (float)pos * div0;
    float a1 = (float)pos * div1;
    e.x += sinf(a0); e.y += cosf(a0);
    e.z += sinf(a1); e.w += cosf(a1);
    *(float4*)(X + (size_t)t * DMODEL + d0) = e;
    *(ushort4*)(Xb + (size_t)t * DMODEL + d0) =
        make_ushort4(f2bf(e.x), f2bf(e.y), f2bf(e.z), f2bf(e.w));
}

// ---------------- generic transpose+convert (fc_w): f32 [R][C] -> bf16 [C][R] ----------------
__global__ __launch_bounds__(256) void transcvt_kernel(const float* __restrict__ in,
                                                       unsigned short* __restrict__ out,
                                                       int R, int C) {
    __shared__ float t[32][33];
    size_t base = (size_t)blockIdx.z * R * C;
    int c0 = blockIdx.x * 32, r0 = blockIdx.y * 32;
    int tx = threadIdx.x & 31, ty = threadIdx.x >> 5;
#pragma unroll
    for (int i = 0; i < 4; i++)
        t[ty + i * 8][tx] = in[base + (size_t)(r0 + ty + i * 8) * C + c0 + tx];
    __syncthreads();
#pragma unroll
    for (int i = 0; i < 4; i++)
        out[base + (size_t)(c0 + ty + i * 8) * R + r0 + tx] = f2bf(t[tx][ty + i * 8]);
}

// ---------------- qkv_w transpose+convert with head-permute + Q prescale ----------------
// out[l][n][k]: n<512 -> Q (head h=n>>6, scaled), n<1024 -> K, else V.
__global__ __launch_bounds__(256) void transcvt_qkv_kernel(const float* __restrict__ in,
                                                           unsigned short* __restrict__ out) {
    __shared__ float t[32][33];
    int l = blockIdx.z;
    int n0 = blockIdx.x * 32, r0 = blockIdx.y * 32;
    int seg = n0 >> 9, nn = n0 & 511, h = nn >> 6, d0 = nn & 63;
    int c0 = h * 192 + seg * 64 + d0;
    float s = (seg == 0) ? QSCALE : 1.f;
    const float* inp = in + (size_t)l * DMODEL * QKVW;
    unsigned short* op = out + (size_t)l * QKVW * DMODEL;
    int tx = threadIdx.x & 31, ty = threadIdx.x >> 5;
#pragma unroll
    for (int i = 0; i < 4; i++)
        t[ty + i * 8][tx] = inp[(size_t)(r0 + ty + i * 8) * QKVW + c0 + tx];
    __syncthreads();
#pragma unroll
    for (int i = 0; i < 4; i++)
        op[(size_t)(n0 + ty + i * 8) * DMODEL + r0 + tx] = f2bf(t[tx][ty + i * 8] * s);
}

// ---------------- permuted (+scaled) qkv bias ----------------
__global__ __launch_bounds__(256) void permbias_kernel(const float* __restrict__ qkv_b,
                                                       float* __restrict__ pb) {
    int i = blockIdx.x * 256 + threadIdx.x;   // < L*1536
    int l = i / QKVW, n = i - l * QKVW;
    int seg = n >> 9, nn = n & 511, h = nn >> 6, d = nn & 63;
    float s = (seg == 0) ? QSCALE : 1.f;
    pb[i] = qkv_b[l * QKVW + h * 192 + seg * 64 + d] * s;
}

// ---------------- QKV GEMM: [M,1536]perm = Xb[M,512] @ Wt^T + pb ----------------
// 128x256 tile, 512 threads / 8 waves, wave = 64x64 (acc[4][4] = 64 regs).
// launch_bounds(512,4): measured-good config (round 10/12, 851us total).
// gload_lds staging, XOR source pre-swizzle, double-buffered, ONE barrier/K-step.
__global__ __launch_bounds__(512, 4) void gemm_qkv_kernel(const unsigned short* __restrict__ A,
                                                          const unsigned short* __restrict__ Bt,
                                                          const float* __restrict__ pb,
                                                          unsigned short* __restrict__ QKc,
                                                          unsigned short* __restrict__ Vt,
                                                          int M) {
    __shared__ unsigned short As[2][128 * 32];
    __shared__ unsigned short Bs[2][256 * 32];
    int bm = blockIdx.y * 128, bn = blockIdx.x * 256;
    int tid = threadIdx.x;
    int w = tid >> 6, lane = tid & 63, l15 = lane & 15, quad = lane >> 4;
    int wm = (w & 1) * 64, wn = (w >> 1) * 64;

    float4v acc[4][4];
    float4v z = {0.f, 0.f, 0.f, 0.f};
#pragma unroll
    for (int i = 0; i < 4; i++)
#pragma unroll
        for (int j = 0; j < 4; j++) acc[i][j] = z;

    // staging geometry: chunk ch covers rows [ch*16, ch*16+16); lane l -> row
    // ch*16 + l/4, pre-swizzled source 8-short chunk ((l&3) ^ ((l>>3)&3)).
    int rsub = lane >> 2;
    int sc = ((lane & 3) ^ ((lane >> 3) & 3)) * 8;
    const unsigned short* Ag = A + (size_t)bm * DMODEL;
    const unsigned short* Bg = Bt + (size_t)bn * DMODEL;

    // prologue: stage kt=0 into buf 0 (wave w: A chunk w, B chunks w and w+8)
    gload16(Ag + (size_t)(w * 16 + rsub) * DMODEL + sc, &As[0][w * 512]);
    gload16(Bg + (size_t)(w * 16 + rsub) * DMODEL + sc, &Bs[0][w * 512]);
    gload16(Bg + (size_t)((w + 8) * 16 + rsub) * DMODEL + sc, &Bs[0][(w + 8) * 512]);
    __syncthreads();

    int sw = (l15 >> 1) & 3;
    for (int kt = 0; kt < 16; kt++) {
        const unsigned short* Ac = As[kt & 1];
        const unsigned short* Bc = Bs[kt & 1];
        if (kt + 1 < 16) {
            int kn = (kt + 1) * 32;
            unsigned short* An = (unsigned short*)As[(kt + 1) & 1];
            unsigned short* Bn = (unsigned short*)Bs[(kt + 1) & 1];
            gload16(Ag + (size_t)(w * 16 + rsub) * DMODEL + kn + sc, &An[w * 512]);
            gload16(Bg + (size_t)(w * 16 + rsub) * DMODEL + kn + sc, &Bn[w * 512]);
            gload16(Bg + (size_t)((w + 8) * 16 + rsub) * DMODEL + kn + sc,
                    &Bn[(w + 8) * 512]);
        }
        short8 af[4], bf[4];
#pragma unroll
        for (int i = 0; i < 4; i++)
            af[i] = *(short8*)&Ac[(wm + i * 16 + l15) * 32 + (quad ^ sw) * 8];
#pragma unroll
        for (int j = 0; j < 4; j++)
            bf[j] = *(short8*)&Bc[(wn + j * 16 + l15) * 32 + (quad ^ sw) * 8];
        __builtin_amdgcn_s_setprio(1);
#pragma unroll
        for (int i = 0; i < 4; i++)
#pragma unroll
            for (int j = 0; j < 4; j++)
                acc[i][j] = MFMA_BF16(af[i], bf[j], acc[i][j], 0, 0, 0);
        __builtin_amdgcn_s_setprio(0);
        __syncthreads();
    }

    float bj[4];
#pragma unroll
    for (int j = 0; j < 4; j++) bj[j] = pb[bn + wn + j * 16 + l15];

    if (bn < 1024) {          // Q | K -> row-major QKc[tok][1024]
#pragma unroll
        for (int i = 0; i < 4; i++)
#pragma unroll
            for (int r = 0; r < 4; r++) {
                size_t row = (size_t)(bm + wm + i * 16 + quad * 4 + r);
#pragma unroll
                for (int j = 0; j < 4; j++)
                    QKc[row * 1024 + bn + wn + j * 16 + l15] = f2bf(acc[i][j][r] + bj[j]);
            }
    } else {                  // V -> transposed Vt[bh][d][s]
        int bl = bm >> 10;
        int sbase = (bm & 1023) + wm;
#pragma unroll
        for (int j = 0; j < 4; j++) {
            int colp = bn - 1024 + wn + j * 16 + l15;
            int h = colp >> 6, d = colp & 63;
            unsigned short* vb = Vt + ((size_t)(bl * 8 + h) * 64 + d) * 1024 + sbase;
#pragma unroll
            for (int i = 0; i < 4; i++) {
                ushort4 v4 = make_ushort4(f2bf(acc[i][j][0] + bj[j]),
                                          f2bf(acc[i][j][1] + bj[j]),
                                          f2bf(acc[i][j][2] + bj[j]),
                                          f2bf(acc[i][j][3] + bj[j]));
                *(ushort4*)(vb + i * 16 + quad * 4) = v4;
            }
        }
    }
}

// ---------------- bf16 MFMA flash attention, max-free softmax ----------------
// (round-6/12 best-measured version: ~117us, VGPR 112, no spill) QBLK=256,
// 256 threads, launch_bounds(256,2). Reg prefetch, swapped QK^T, in-register
// softmax via cvt_pk + permlane swaps. NOTE: (256,3) and 512-thread variants
// both spill catastrophically (r7: +6MB scratch; r13: 981MB scratch, 3.5x).
__global__ __launch_bounds__(256, 2) void attn_kernel(const unsigned short* __restrict__ QKc,
                                                      const unsigned short* __restrict__ Vt,
                                                      unsigned short* __restrict__ O) {
    __shared__ unsigned short Ks[64 * 72];    // K[kcol][d]
    __shared__ unsigned short Vts[64 * 72];   // V^T[d][k]
    int bh = blockIdx.y;
    int b = bh >> 3, h = bh & 7;
    int q0 = blockIdx.x * 256;
    int tid = threadIdx.x;
    int w = tid >> 6, lane = tid & 63, l15 = lane & 15, quad = lane >> 4;
    const unsigned short* Kg = QKc + (size_t)b * SEQ * 1024 + 512 + h * 64;
    const unsigned short* Vg = Vt + (size_t)bh * 64 * 1024;

    short8 qf[4][2];
#pragma unroll
    for (int i = 0; i < 4; i++) {
        const unsigned short* qb =
            QKc + (size_t)(b * SEQ + q0 + w * 64 + i * 16 + l15) * 1024 + h * 64;
        qf[i][0] = *(const short8*)(qb + quad * 8);
        qf[i][1] = *(const short8*)(qb + 32 + quad * 8);
    }

    float lsum[4] = {0.f, 0.f, 0.f, 0.f};
    float4v accO[4][4];
    float4v z = {0.f, 0.f, 0.f, 0.f};
#pragma unroll
    for (int i = 0; i < 4; i++)
#pragma unroll
        for (int dc = 0; dc < 4; dc++) accO[i][dc] = z;

    int sr = tid >> 2, so = (tid & 3) * 16;   // staging: row, 16-col chunk

    // prefetch tile 0 into regs
    short8 kp0, kp1, vp0, vp1;
    {
        const unsigned short* kg = Kg + (size_t)sr * 1024 + so;
        kp0 = *(const short8*)kg;
        kp1 = *(const short8*)(kg + 8);
        const unsigned short* vg = Vg + (size_t)sr * 1024 + so;
        vp0 = *(const short8*)vg;
        vp1 = *(const short8*)(vg + 8);
    }

    for (int jt = 0; jt < SEQ / 64; jt++) {
        __syncthreads();
        *(short8*)&Ks[sr * 72 + so] = kp0;
        *(short8*)&Ks[sr * 72 + so + 8] = kp1;
        *(short8*)&Vts[sr * 72 + so] = vp0;
        *(short8*)&Vts[sr * 72 + so + 8] = vp1;
        __syncthreads();

        // prefetch next tile (latency hides under this tile's compute)
        if (jt + 1 < SEQ / 64) {
            const unsigned short* kg = Kg + (size_t)((jt + 1) * 64 + sr) * 1024 + so;
            kp0 = *(const short8*)kg;
            kp1 = *(const short8*)(kg + 8);
            const unsigned short* vg = Vg + (size_t)sr * 1024 + (jt + 1) * 64 + so;
            vp0 = *(const short8*)vg;
            vp1 = *(const short8*)(vg + 8);
        }

        // S^T: lane (l15,quad) reg r holds S[q=i*16+l15][k=jc*16+quad*4+r].
        // One kf pair feeds all 4 i's.
        short8 pa[4][2];
#pragma unroll
        for (int f = 0; f < 2; f++) {
            float4v st[4][2];
#pragma unroll
            for (int jj = 0; jj < 2; jj++) {
                int jc = f * 2 + jj;
                short8 kf0 = *(short8*)&Ks[(jc * 16 + l15) * 72 + quad * 8];
                short8 kf1 = *(short8*)&Ks[(jc * 16 + l15) * 72 + 32 + quad * 8];
#pragma unroll
                for (int i = 0; i < 4; i++) {
                    float4v s0 = MFMA_BF16(kf0, qf[i][0], z, 0, 0, 0);
                    st[i][jj] = MFMA_BF16(kf1, qf[i][1], s0, 0, 0, 0);
                }
            }
#pragma unroll
            for (int i = 0; i < 4; i++) {
                unsigned int pk[4];
#pragma unroll
                for (int jj = 0; jj < 2; jj++) {
                    float p0 = exp2f(st[i][jj][0]);
                    float p1 = exp2f(st[i][jj][1]);
                    float p2 = exp2f(st[i][jj][2]);
                    float p3 = exp2f(st[i][jj][3]);
                    lsum[i] += (p0 + p1) + (p2 + p3);
                    pk[jj * 2 + 0] = cvt_pk_bf16(p0, p1);
                    pk[jj * 2 + 1] = cvt_pk_bf16(p2, p3);
                }
                // dst(l5,l4,r1,r0) <- src(l4,r1,l5,r0): 2x permlane32 + 2x permlane16
                PL32(pk[0], pk[2]);
                PL32(pk[1], pk[3]);
                PL16(pk[0], pk[2]);
                PL16(pk[1], pk[3]);
                uint4v t;
                t[0] = pk[0]; t[1] = pk[1]; t[2] = pk[2]; t[3] = pk[3];
                pa[i][f] = __builtin_bit_cast(short8, t);
            }
        }

        // PV: one vf pair feeds all 4 i's
        __builtin_amdgcn_s_setprio(1);
#pragma unroll
        for (int dc = 0; dc < 4; dc++) {
            short8 vf0 = *(short8*)&Vts[(dc * 16 + l15) * 72 + quad * 8];
            short8 vf1 = *(short8*)&Vts[(dc * 16 + l15) * 72 + 32 + quad * 8];
#pragma unroll
            for (int i = 0; i < 4; i++) {
                accO[i][dc] = MFMA_BF16(pa[i][0], vf0, accO[i][dc], 0, 0, 0);
                accO[i][dc] = MFMA_BF16(pa[i][1], vf1, accO[i][dc], 0, 0, 0);
            }
        }
        __builtin_amdgcn_s_setprio(0);
    }

    // epilogue: reduce row sums across the 4 quads, fetch per-row sum, normalize
#pragma unroll
    for (int i = 0; i < 4; i++) {
        float s = lsum[i];
        s += __shfl_xor(s, 16);
        s += __shfl_xor(s, 32);   // all lanes now hold total for q = i*16 + l15
#pragma unroll
        for (int r = 0; r < 4; r++) {
            float rinv = 1.f / __shfl(s, quad * 4 + r);
            size_t row = (size_t)(b * SEQ + q0 + w * 64 + i * 16 + quad * 4 + r);
#pragma unroll
            for (int dc = 0; dc < 4; dc++)
                O[row * DMODEL + h * DHEAD + dc * 16 + l15] = f2bf(accO[i][dc][r] * rinv);
        }
    }
}

// ---------------- fused out-proj + bias + residual + LayerNorm ----------------
// (round-10 best-measured version) M=64 per block, 256 threads, acc[4][8];
// halves per-dispatch B-panel re-staging vs M=32 and doubles MFMA per B LDS-read.
// Post-residual values stored IN PLACE into acc. gload_lds staging,
// double-buffered, one barrier per K-step.
__global__ __launch_bounds__(256, 2) void proj_ln_kernel(const unsigned short* __restrict__ A,
                                                         const unsigned short* __restrict__ Bt,
                                                         const float* __restrict__ bias,
                                                         const float* __restrict__ gamma,
                                                         const float* __restrict__ beta,
                                                         float* __restrict__ X,
                                                         unsigned short* __restrict__ Xb) {
    __shared__ unsigned short As2[2][64 * 32];
    __shared__ unsigned short Bs2[2][512 * 32];
    __shared__ float redS[4][64], redQ[4][64];
    int bm = blockIdx.x * 64;
    int tid = threadIdx.x;
    int w = tid >> 6, lane = tid & 63, l15 = lane & 15, quad = lane >> 4;
    int wn = w * 128;

    float4v acc[4][8];
    float4v z = {0.f, 0.f, 0.f, 0.f};
#pragma unroll
    for (int i = 0; i < 4; i++)
#pragma unroll
        for (int j = 0; j < 8; j++) acc[i][j] = z;

    int lrow4 = lane >> 2;
    int sc = ((lane & 3) ^ ((lane >> 3) & 3)) * 8;
    const unsigned short* Ag = A + (size_t)bm * DMODEL;

    // prologue: stage kt=0 into buf 0 (wave w: A chunk w, B chunks w*8..w*8+7)
    gload16(Ag + (size_t)(w * 16 + lrow4) * DMODEL + sc, &As2[0][w * 512]);
#pragma unroll
    for (int u = 0; u < 8; u++) {
        int ch = w * 8 + u;
        gload16(Bt + (size_t)(ch * 16 + lrow4) * DMODEL + sc, &Bs2[0][ch * 512]);
    }
    __syncthreads();

    int sw = (l15 >> 1) & 3;
    for (int kt = 0; kt < 16; kt++) {
        const unsigned short* Ac = As2[kt & 1];
        const unsigned short* Bc = Bs2[kt & 1];
        if (kt + 1 < 16) {
            int kn = (kt + 1) * 32;
            unsigned short* An = (unsigned short*)As2[(kt + 1) & 1];
            unsigned short* Bn = (unsigned short*)Bs2[(kt + 1) & 1];
            gload16(Ag + (size_t)(w * 16 + lrow4) * DMODEL + kn + sc, &An[w * 512]);
#pragma unroll
            for (int u = 0; u < 8; u++) {
                int ch = w * 8 + u;
                gload16(Bt + (size_t)(ch * 16 + lrow4) * DMODEL + kn + sc, &Bn[ch * 512]);
            }
        }
        short8 af[4];
#pragma unroll
        for (int i = 0; i < 4; i++)
            af[i] = *(short8*)&Ac[(i * 16 + l15) * 32 + (quad ^ sw) * 8];
        __builtin_amdgcn_s_setprio(1);
#pragma unroll
        for (int j = 0; j < 8; j++) {
            short8 bf = *(short8*)&Bc[(wn + j * 16 + l15) * 32 + (quad ^ sw) * 8];
#pragma unroll
            for (int i = 0; i < 4; i++)
                acc[i][j] = MFMA_BF16(af[i], bf, acc[i][j], 0, 0, 0);
        }
        __builtin_amdgcn_s_setprio(0);
        __syncthreads();
    }

    float bj[8], g[8], be[8];
#pragma unroll
    for (int j = 0; j < 8; j++) {
        int col = wn + j * 16 + l15;
        bj[j] = bias[col]; g[j] = gamma[col]; be[j] = beta[col];
    }

#pragma unroll
    for (int i = 0; i < 4; i++)
#pragma unroll
        for (int r = 0; r < 4; r++) {
            int lrow = i * 16 + quad * 4 + r;
            size_t row = (size_t)(bm + lrow);
            float ss = 0.f, qq = 0.f;
#pragma unroll
            for (int j = 0; j < 8; j++) {
                float v = acc[i][j][r] + bj[j] + X[row * DMODEL + wn + j * 16 + l15];
                acc[i][j][r] = v;          // in-place: acc becomes post-residual o
                ss += v; qq += v * v;
            }
#pragma unroll
            for (int mask = 1; mask < 16; mask <<= 1) {
                ss += __shfl_xor(ss, mask);
                qq += __shfl_xor(qq, mask);
            }
            if (l15 == 0) { redS[w][lrow] = ss; redQ[w][lrow] = qq; }
        }
    __syncthreads();
#pragma unroll
    for (int i = 0; i < 4; i++)
#pragma unroll
        for (int r = 0; r < 4; r++) {
            int lrow = i * 16 + quad * 4 + r;
            float S = redS[0][lrow] + redS[1][lrow] + redS[2][lrow] + redS[3][lrow];
            float Q = redQ[0][lrow] + redQ[1][lrow] + redQ[2][lrow] + redQ[3][lrow];
            float mean = S * (1.f / 512.f);
            float var = Q * (1.f / 512.f) - mean * mean;
            float rstd = rsqrtf(var + 1e-5f);
            size_t row = (size_t)(bm + lrow);
#pragma unroll
            for (int j = 0; j < 8; j++) {
                float n = (acc[i][j][r] - mean) * rstd * g[j] + be[j];
                X[row * DMODEL + wn + j * 16 + l15] = n;
                Xb[row * DMODEL + wn + j * 16 + l15] = f2bf(n);
            }
        }
}

// ---------------- pooled zero + two-stage mean pool ----------------
__global__ __launch_bounds__(256) void zero_kernel(float* __restrict__ p) {
    p[blockIdx.x * 256 + threadIdx.x] = 0.f;
}
__global__ __launch_bounds__(128) void pool_kernel(const float* __restrict__ X,
                                                   float* __restrict__ pooled) {
    int b = blockIdx.x, ch = blockIdx.y;
    int d0 = threadIdx.x * 4;
    float4 acc = make_float4(0.f, 0.f, 0.f, 0.f);
    const float* base = X + (size_t)(b * SEQ + ch * 64) * DMODEL + d0;
    for (int s2 = 0; s2 < 64; s2++) {
        float4 v = *(const float4*)(base + (size_t)s2 * DMODEL);
        acc.x += v.x; acc.y += v.y; acc.z += v.z; acc.w += v.w;
    }
    atomicAdd(pooled + b * DMODEL + d0 + 0, acc.x);
    atomicAdd(pooled + b * DMODEL + d0 + 1, acc.y);
    atomicAdd(pooled + b * DMODEL + d0 + 2, acc.z);
    atomicAdd(pooled + b * DMODEL + d0 + 3, acc.w);
}

// ---------------- MLP head ----------------
__global__ __launch_bounds__(256) void fc1_kernel(const float* __restrict__ pooled,
                                                  const float* __restrict__ fc1_w,
                                                  const float* __restrict__ fc1_b,
                                                  float* __restrict__ h) {
    __shared__ float p[DMODEL];
    int ffc = blockIdx.x, b = blockIdx.y;
    int tid = threadIdx.x;
    p[tid] = pooled[b * DMODEL + tid] * (1.f / 1024.f);
    p[tid + 256] = pooled[b * DMODEL + tid + 256] * (1.f / 1024.f);
    __syncthreads();
    int ff = ffc * 256 + tid;
    float acc = fc1_b[ff];
    for (int k = 0; k < DMODEL; k++) acc += p[k] * fc1_w[(size_t)k * FFDIM + ff];
    h[(size_t)b * FFDIM + ff] = fmaxf(acc, 0.f);
}

__global__ __launch_bounds__(256) void fc2_kernel(const float* __restrict__ h,
                                                  const float* __restrict__ fc2_w,
                                                  const float* __restrict__ fc2_b,
                                                  float* __restrict__ out) {
    __shared__ float red[NCLS][256];
    int b = blockIdx.x, tid = threadIdx.x;
    float a[NCLS];
#pragma unroll
    for (int c = 0; c < NCLS; c++) a[c] = 0.f;
    int k0 = tid * 8;
#pragma unroll
    for (int u = 0; u < 8; u++) {
        float hv = h[(size_t)b * FFDIM + k0 + u];
#pragma unroll
        for (int c = 0; c < NCLS; c++) a[c] += hv * fc2_w[(k0 + u) * NCLS + c];
    }
#pragma unroll
    for (int c = 0; c < NCLS; c++) red[c][tid] = a[c];
    __syncthreads();
    if (tid < NCLS) {
        float s = 0.f;
        for (int i = 0; i < 256; i++) s += red[tid][i];
        out[b * NCLS + tid] = s + fc2_b[tid];
    }
}

extern "C" void kernel_launch(void* const* d_in, const int* in_sizes, int n_in,
                              void* d_out, int out_size, void* d_ws, size_t ws_size,
                              hipStream_t stream) {
    const int* tokens = (const int*)d_in[0];
    const float* emb = (const float*)d_in[1];
    const float* qkv_w = (const float*)d_in[2];
    const float* qkv_b = (const float*)d_in[3];
    const float* fc_w = (const float*)d_in[4];
    const float* fc_b = (const float*)d_in[5];
    const float* gamma = (const float*)d_in[6];
    const float* beta = (const float*)d_in[7];
    const float* fc1_w = (const float*)d_in[8];
    const float* fc1_b = (const float*)d_in[9];
    const float* fc2_w = (const float*)d_in[10];
    const float* fc2_b = (const float*)d_in[11];
    float* out = (float*)d_out;

    char* p = (char*)d_ws;
    float* X = (float*)p;                         p += (size_t)BS_TOK * DMODEL * 4;  // 64 MB
    unsigned short* Xb = (unsigned short*)p;      p += (size_t)BS_TOK * DMODEL * 2;  // 32 MB
    float* pooled = (float*)p;                    p += (size_t)BATCH * DMODEL * 4;
    float* hbuf = (float*)p;                      p += (size_t)BATCH * FFDIM * 4;
    float* pb = (float*)p;                        p += (size_t)NLAYER * QKVW * 4;
    unsigned short* qkv_wbt = (unsigned short*)p; p += (size_t)NLAYER * QKVW * DMODEL * 2;
    unsigned short* fc_wt = (unsigned short*)p;   p += (size_t)NLAYER * DMODEL * DMODEL * 2;
    size_t fixed_bytes = (size_t)(p - (char*)d_ws);
    // per batch: QKc 2MB + Vt 1MB + Oc 1MB
    size_t per_batch = (size_t)SEQ * 1024 * 2 + (size_t)NHEAD * 64 * SEQ * 2
                     + (size_t)SEQ * DMODEL * 2;
    int chunkB = 1;
    for (int cb = 32; cb >= 1; cb >>= 1)
        if (fixed_bytes + (size_t)cb * per_batch <= ws_size) { chunkB = cb; break; }
    unsigned short* QKc = (unsigned short*)p;     p += (size_t)chunkB * SEQ * 1024 * 2;
    unsigned short* Vt = (unsigned short*)p;      p += (size_t)chunkB * NHEAD * 64 * SEQ * 2;
    unsigned short* Oc = (unsigned short*)p;
    int rows = chunkB * SEQ;
    int nchunks = BATCH / chunkB;

    embed_pe_kernel<<<BS_TOK, 128, 0, stream>>>(tokens, emb, X, Xb);
    permbias_kernel<<<NLAYER * QKVW / 256, 256, 0, stream>>>(qkv_b, pb);
    transcvt_qkv_kernel<<<dim3(QKVW / 32, DMODEL / 32, NLAYER), 256, 0, stream>>>(
        qkv_w, qkv_wbt);
    transcvt_kernel<<<dim3(DMODEL / 32, DMODEL / 32, NLAYER), 256, 0, stream>>>(
        fc_w, fc_wt, DMODEL, DMODEL);

    for (int l = 0; l < NLAYER; l++) {
        for (int c = 0; c < nchunks; c++) {
            unsigned short* Xbc = Xb + (size_t)c * rows * DMODEL;
            float* Xc = X + (size_t)c * rows * DMODEL;
            gemm_qkv_kernel<<<dim3(QKVW / 256, rows / 128), 512, 0, stream>>>(
                Xbc, qkv_wbt + (size_t)l * QKVW * DMODEL, pb + (size_t)l * QKVW,
                QKc, Vt, rows);
            attn_kernel<<<dim3(SEQ / 256, chunkB * NHEAD), 256, 0, stream>>>(QKc, Vt, Oc);
            proj_ln_kernel<<<rows / 64, 256, 0, stream>>>(
                Oc, fc_wt + (size_t)l * DMODEL * DMODEL, fc_b + (size_t)l * DMODEL,
                gamma, beta, Xc, Xbc);
        }
    }

    zero_kernel<<<BATCH * DMODEL / 256, 256, 0, stream>>>(pooled);
    pool_kernel<<<dim3(BATCH, 16), 128, 0, stream>>>(X, pooled);
    fc1_kernel<<<dim3(FFDIM / 256, BATCH), 256, 0, stream>>>(pooled, fc1_w, fc1_b, hbuf);
    fc2_kernel<<<BATCH, 256, 0, stream>>>(hbuf, fc2_w, fc2_b, out);
}